// Round 3
// baseline (3143.610 us; speedup 1.0000x reference)
//
#include <hip/hip_runtime.h>

#define DIN 512
#define DH  64
#define BKT_SHIFT 10                // 1024 nodes per bucket
#define BKT_NODES 1024
#define MAXBKT 128                  // supports up to 131072 nodes
#define TILE 8192                   // edges per binning workgroup
#define SRC_BITS 17                 // n_nodes < 131072
#define SRC_MASK ((1u << SRC_BITS) - 1)
#define QN 256                      // dst nodes per gather workgroup (quarter-bucket)
#define ASTRIDE 65                  // LDS acc row stride (floats): bank = dl+8cg+k mod 32

typedef __attribute__((ext_vector_type(8))) _Float16 half8_t;
typedef __attribute__((ext_vector_type(4))) float float4_t;

// ---- fused prep + bin (grid-partitioned):
//  block 0:    Wc=W2@Wlin -> Wct fp16, bias_out=b2@Wlin+blin
//  blocks 1-4: Wt fp16 [n][k] = W1^T slice via LDS transpose
//  blocks 5+:  bin tile (blockIdx.x-5) of edges into fixed-cap bucket regions
__global__ __launch_bounds__(256) void k_prepbin(const float* __restrict__ W1,
                                                 const float* __restrict__ W2,
                                                 const float* __restrict__ b2,
                                                 const float* __restrict__ Wlin,
                                                 const float* __restrict__ blin,
                                                 _Float16* __restrict__ Wt,
                                                 _Float16* __restrict__ Wct,
                                                 float* __restrict__ bias_out,
                                                 const int* __restrict__ src,
                                                 const int* __restrict__ dst,
                                                 int n_edges,
                                                 int* __restrict__ gcur,
                                                 unsigned int* __restrict__ tmp,
                                                 int nbkt, int cap) {
  const int tid = threadIdx.x;
  if (blockIdx.x == 0) {
    __shared__ float WcS[64 * 64];
    for (int idx = tid; idx < 64 * 64; idx += 256) {
      int i = idx >> 6, j = idx & 63;
      float s = 0.f;
      #pragma unroll 8
      for (int k = 0; k < 64; ++k) s = fmaf(W2[i * 64 + k], Wlin[k * 64 + j], s);
      WcS[idx] = s;
    }
    if (tid < 64) {
      float s = blin[tid];
      #pragma unroll 8
      for (int k = 0; k < 64; ++k) s = fmaf(b2[k], Wlin[k * 64 + tid], s);
      bias_out[tid] = s;
    }
    __syncthreads();
    for (int G = tid; G < 64 * 64 / 8; G += 256) {
      int n = G >> 3, k = (G & 7) * 8;
      half8_t h;
      #pragma unroll
      for (int j = 0; j < 8; ++j) h[j] = (_Float16)WcS[(k + j) * 64 + n];
      *(half8_t*)&Wct[(size_t)n * 64 + k] = h;
    }
  } else if (blockIdx.x <= 4) {
    __shared__ _Float16 T[64][136];
    const int k0 = (blockIdx.x - 1) * 128;
    for (int idx = tid; idx < 128 * 64; idx += 256) {
      int kk = idx >> 6, n = idx & 63;
      T[n][kk] = (_Float16)W1[(size_t)(k0 + kk) * 64 + n];
    }
    __syncthreads();
    for (int G = tid; G < 64 * 16; G += 256) {
      int n = G >> 4, g = (G & 15) * 8;
      half8_t h = *(const half8_t*)&T[n][g];
      *(half8_t*)&Wt[(size_t)n * 512 + k0 + g] = h;
    }
  } else {
    __shared__ int cnt[MAXBKT];
    __shared__ int base[MAXBKT];
    for (int b = tid; b < nbkt; b += 256) cnt[b] = 0;
    __syncthreads();
    int e0 = (blockIdx.x - 5) * TILE;
    int e1 = min(e0 + TILE, n_edges);
    for (int e = e0 + tid; e < e1; e += 256)
      atomicAdd(&cnt[dst[e] >> BKT_SHIFT], 1);
    __syncthreads();
    for (int b = tid; b < nbkt; b += 256) {
      int c = cnt[b];
      base[b] = c ? (b * cap + atomicAdd(&gcur[b], c)) : 0;
      cnt[b] = 0;
    }
    __syncthreads();
    for (int e = e0 + tid; e < e1; e += 256) {
      int d = dst[e];
      int bkt = d >> BKT_SHIFT;
      int off = atomicAdd(&cnt[bkt], 1);
      int pos = base[bkt] + off;
      if (pos < (bkt + 1) * cap)  // overflow guard (never hit for random dst)
        tmp[pos] = (unsigned int)src[e] |
                   ((unsigned int)(d & (BKT_NODES - 1)) << SRC_BITS);
    }
  }
}

// ------- per-bucket: degrees -> dinv; counting-sort edges by
//         key = (dst_quarter, src>>9) so the gather streams src-local windows.
//         qbeg[bkt*4+q] = exclusive offset of quarter q within the bucket.
__global__ __launch_bounds__(256) void k_place(const unsigned int* __restrict__ tmp,
                                               const int* __restrict__ gcur,
                                               float* __restrict__ dinv,
                                               unsigned int* __restrict__ srcs,
                                               int* __restrict__ qbeg,
                                               int n_nodes, int cap) {
  __shared__ int deg[BKT_NODES];
  __shared__ int kcnt[1024];
  __shared__ int sh[256];
  const int t = threadIdx.x;
  const int bkt = blockIdx.x;
  #pragma unroll
  for (int k = 0; k < 4; ++k) { deg[t + 256 * k] = 0; kcnt[t + 256 * k] = 0; }
  __syncthreads();
  const int beg = bkt * cap;
  const int end = beg + min(gcur[bkt], cap);
  for (int j = beg + t; j < end; j += 256) {
    unsigned int w = tmp[j];
    int dl = (int)(w >> SRC_BITS);                       // 0..1023
    int key = ((dl >> 8) << 8) | (int)((w & SRC_MASK) >> 9);
    atomicAdd(&deg[dl], 1);
    atomicAdd(&kcnt[key], 1);
  }
  __syncthreads();
  #pragma unroll
  for (int k = 0; k < 4; ++k) {
    int idx = t + 256 * k;
    int node = (bkt << BKT_SHIFT) + idx;
    if (node < n_nodes) dinv[node] = rsqrtf((float)(deg[idx] + 1));  // +1 self loop
  }
  // exclusive scan of kcnt (1024 bins, 4 per thread)
  int v[4];
  int s = 0;
  const int base4 = t * 4;
  #pragma unroll
  for (int k = 0; k < 4; ++k) {
    v[k] = kcnt[base4 + k];
    s += v[k];
  }
  sh[t] = s;
  __syncthreads();
  for (int off = 1; off < 256; off <<= 1) {
    int x = sh[t];
    int y = (t >= off) ? sh[t - off] : 0;
    __syncthreads();
    sh[t] = x + y;
    __syncthreads();
  }
  int excl = sh[t] - s;
  #pragma unroll
  for (int k = 0; k < 4; ++k) {
    int idx = base4 + k;
    if ((idx & 255) == 0) qbeg[bkt * 4 + (idx >> 8)] = excl;
    kcnt[idx] = excl;           // becomes the running cursor
    excl += v[k];
  }
  __syncthreads();
  for (int j = beg + t; j < end; j += 256) {
    unsigned int w = tmp[j];
    int dl = (int)(w >> SRC_BITS);
    int key = ((dl >> 8) << 8) | (int)((w & SRC_MASK) >> 9);
    int pos = atomicAdd(&kcnt[key], 1);
    srcs[beg + pos] = w;
  }
}

// ---- MFMA fp16 GEMM + row scaling: Ch[r,:] = (fp16)( (A[r,:] @ Bt^T) * dinv[r] )
// 1024 threads = 16 waves, 256 rows/block. Bt [64][KDIM] fp16, LDS-swizzled.
// NOTE: A-operand row index = lane&15, but C/D output row = (lane>>4)*4 + reg.
// dinv must be indexed by the OUTPUT row (bug fixed in R11).
template <int KDIM, bool A_HALF>
__global__ __launch_bounds__(1024) void k_mfma(const void* __restrict__ Ain,
                                               const _Float16* __restrict__ Bt,
                                               const float* __restrict__ dinv,
                                               _Float16* __restrict__ Ch, int M) {
  constexpr int BS_HALVES = (64 * KDIM > 16384) ? 64 * KDIM : 16384;
  __shared__ _Float16 Bs[BS_HALVES];  // 64KB (K=512) / 32KB (K=64)
  const int tid = threadIdx.x;
  for (int G = tid; G < 8 * KDIM; G += 1024) {
    int n = G / (KDIM / 8);
    int g = G % (KDIM / 8);
    half8_t h = *(const half8_t*)&Bt[(size_t)G * 8];
    *(half8_t*)&Bs[n * KDIM + ((g ^ (n & 7)) * 8)] = h;
  }
  __syncthreads();

  const int wave = tid >> 6, lane = tid & 63;
  const int quad = lane >> 4, lrow = lane & 15;
  const int row = blockIdx.x * 256 + wave * 16 + lrow;
  const int rowc = min(row, M - 1);

  float4_t acc[4] = {{0.f, 0.f, 0.f, 0.f}, {0.f, 0.f, 0.f, 0.f},
                     {0.f, 0.f, 0.f, 0.f}, {0.f, 0.f, 0.f, 0.f}};

  #pragma unroll
  for (int k0 = 0; k0 < KDIM; k0 += 32) {
    half8_t a;
    if (A_HALF) {
      a = *(const half8_t*)((const _Float16*)Ain + (size_t)rowc * KDIM + k0 + quad * 8);
    } else {
      const float* Af = (const float*)Ain + (size_t)rowc * KDIM + k0 + quad * 8;
      float4 x0 = *(const float4*)Af;
      float4 x1 = *(const float4*)(Af + 4);
      a[0] = (_Float16)x0.x; a[1] = (_Float16)x0.y;
      a[2] = (_Float16)x0.z; a[3] = (_Float16)x0.w;
      a[4] = (_Float16)x1.x; a[5] = (_Float16)x1.y;
      a[6] = (_Float16)x1.z; a[7] = (_Float16)x1.w;
    }
    const int g = (k0 >> 3) + quad;
    #pragma unroll
    for (int nb = 0; nb < 4; ++nb) {
      int n = nb * 16 + lrow;
      half8_t b = *(const half8_t*)&Bs[n * KDIM + ((g ^ (n & 7)) * 8)];
      acc[nb] = __builtin_amdgcn_mfma_f32_16x16x32_f16(a, b, acc[nb], 0, 0, 0);
    }
  }

  // per-OUTPUT-row dinv (output row = wave*16 + quad*4 + r)
  const int orow_base = blockIdx.x * 256 + wave * 16 + quad * 4;
  float dnr[4];
  #pragma unroll
  for (int r = 0; r < 4; ++r) dnr[r] = dinv[min(orow_base + r, M - 1)];

  __syncthreads();
  _Float16* scratch = Bs + wave * 1024;  // 16x64 halves per wave
  #pragma unroll
  for (int nb = 0; nb < 4; ++nb)
    #pragma unroll
    for (int r = 0; r < 4; ++r)
      scratch[(quad * 4 + r) * 64 + nb * 16 + lrow] = (_Float16)(acc[nb][r] * dnr[r]);
  const int r2 = lane >> 2, c2 = (lane & 3) * 16;
  const int row_out = blockIdx.x * 256 + wave * 16 + r2;
  half8_t o0 = *(const half8_t*)&scratch[r2 * 64 + c2];
  half8_t o1 = *(const half8_t*)&scratch[r2 * 64 + c2 + 8];
  if (row_out < M) {
    *(half8_t*)&Ch[(size_t)row_out * 64 + c2] = o0;
    *(half8_t*)&Ch[(size_t)row_out * 64 + c2 + 8] = o1;
  }
}

// ---- scatter-gather: per quarter-bucket (256 dst nodes) accumulate in LDS.
// Edges sorted by (quarter, src>>9): srcs streamed, fs reads confined to a
// sliding 128 KB window shared by all co-resident workgroups -> L2 hits.
// grid = (nbkt, 4), 1024 threads (8 edge-parallel waves), 66.5 KB LDS (2 wg/CU).
// out = act( dinv[n]*( sum_e fs[s_e,:] + fs[n,:] ) + bias )
__global__ __launch_bounds__(1024) void k_gather(const _Float16* __restrict__ fs,
                                                 const unsigned int* __restrict__ srcs,
                                                 const int* __restrict__ gcur,
                                                 const int* __restrict__ qbeg,
                                                 const float* __restrict__ dinv,
                                                 const float* __restrict__ bias,
                                                 _Float16* __restrict__ outh,
                                                 float* __restrict__ outf,
                                                 int n_nodes, int cap) {
  __shared__ float acc[QN * ASTRIDE];
  const int tid = threadIdx.x;
  const int bkt = blockIdx.x, q = blockIdx.y;
  for (int i = tid; i < QN * ASTRIDE; i += 1024) acc[i] = 0.f;
  __syncthreads();
  const int base = bkt * cap;
  const int total = min(gcur[bkt], cap);
  const int e0 = base + qbeg[bkt * 4 + q];
  const int e1 = base + ((q == 3) ? total : qbeg[bkt * 4 + q + 1]);
  const int esub = tid >> 3;        // 0..127 edge slot
  const int cg = (tid & 7) * 8;     // channel group base
  for (int j = e0; j < e1; j += 128) {
    int idx = j + esub;
    if (idx < e1) {
      unsigned int w = srcs[idx];
      int s = (int)(w & SRC_MASK);
      int dq = (int)((w >> SRC_BITS) & (QN - 1));   // dst_local within quarter
      half8_t f = *(const half8_t*)&fs[(size_t)s * 64 + cg];
      float* ap = &acc[dq * ASTRIDE + cg];
      #pragma unroll
      for (int k = 0; k < 8; ++k) atomicAdd(&ap[k], (float)f[k]);
    }
  }
  __syncthreads();
  for (int v = tid; v < QN * 8; v += 1024) {
    int nl = v >> 3, cge = (v & 7) * 8;
    int node = (bkt << BKT_SHIFT) + q * QN + nl;
    if (node >= n_nodes) continue;
    float dn = dinv[node];
    half8_t sf = *(const half8_t*)&fs[(size_t)node * 64 + cge];
    float o[8];
    #pragma unroll
    for (int k = 0; k < 8; ++k)
      o[k] = fmaf(acc[nl * ASTRIDE + cge + k] + (float)sf[k], dn, bias[cge + k]);
    if (outh) {
      half8_t oh;
      #pragma unroll
      for (int k = 0; k < 8; ++k) oh[k] = (_Float16)fmaxf(o[k], 0.f);
      *(half8_t*)&outh[(size_t)node * 64 + cge] = oh;
    } else {
      *(float4*)&outf[(size_t)node * 64 + cge] = make_float4(o[0], o[1], o[2], o[3]);
      *(float4*)&outf[(size_t)node * 64 + cge + 4] = make_float4(o[4], o[5], o[6], o[7]);
    }
  }
}

extern "C" void kernel_launch(void* const* d_in, const int* in_sizes, int n_in,
                              void* d_out, int out_size, void* d_ws, size_t ws_size,
                              hipStream_t stream) {
  const float* x    = (const float*)d_in[0];
  const int*   ei   = (const int*)d_in[1];
  const float* W1   = (const float*)d_in[2];
  const float* b1   = (const float*)d_in[3];
  const float* W2   = (const float*)d_in[4];
  const float* b2   = (const float*)d_in[5];
  const float* Wlin = (const float*)d_in[6];
  const float* blin = (const float*)d_in[7];
  float* out = (float*)d_out;

  const int n_nodes = in_sizes[0] / DIN;
  const int n_edges = in_sizes[1] / 2;
  const int* src = ei;
  const int* dst = ei + n_edges;
  const int nbkt = (n_nodes + BKT_NODES - 1) >> BKT_SHIFT;
  const int ntiles = (n_edges + TILE - 1) / TILE;
  const int cap = ((n_edges / nbkt) * 5 / 4 + 1024 + 255) & ~255;  // bucket capacity

  char* ws = (char*)d_ws;
  size_t off = 0;
  auto alloc = [&](size_t bytes) {
    void* p = ws + off;
    off += (bytes + 255) & ~(size_t)255;
    return p;
  };
  const size_t featH = (size_t)n_nodes * DH * 2;
  const size_t padE = (size_t)nbkt * cap;
  _Float16*     fs1      = (_Float16*)alloc(featH);   // (x@W1)*dinv fp16 [N][64]
  _Float16*     h1r      = (_Float16*)alloc(featH);   // relu'd layer-1 out fp16 [N][64]
  _Float16*     fs2      = (_Float16*)alloc(featH);   // (h1r@Wc)*dinv fp16 [N][64]
  unsigned int* tmp      = (unsigned int*)alloc(padE * 4);
  unsigned int* srcs     = (unsigned int*)alloc(padE * 4);  // sorted packed edges
  float*        dinv     = (float*)alloc((size_t)n_nodes * 4);
  int*          qbeg     = (int*)alloc((size_t)MAXBKT * 4 * 4);
  int*          gcur     = (int*)alloc((size_t)MAXBKT * 4);
  _Float16*     Wt       = (_Float16*)alloc(64 * 512 * 2);
  _Float16*     Wct      = (_Float16*)alloc(64 * 64 * 2);
  float*        bias_out = (float*)alloc(64 * 4);

  hipMemsetAsync(gcur, 0, (size_t)nbkt * 4, stream);

  k_prepbin<<<5 + ntiles, 256, 0, stream>>>(W1, W2, b2, Wlin, blin, Wt, Wct,
                                            bias_out, src, dst, n_edges, gcur,
                                            tmp, nbkt, cap);
  k_place<<<nbkt, 256, 0, stream>>>(tmp, gcur, dinv, srcs, qbeg, n_nodes, cap);

  const int mblocks = (n_nodes + 255) / 256;
  const dim3 gg(nbkt, 4);   // quarter-buckets

  // layer 1: fs1 = (x@W1)*dinv (fp16 MFMA), gather -> h1r (fp16, ReLU fused)
  k_mfma<512, false><<<mblocks, 1024, 0, stream>>>(x, Wt, dinv, fs1, n_nodes);
  k_gather<<<gg, 1024, 0, stream>>>(fs1, srcs, gcur, qbeg, dinv, b1,
                                    h1r, nullptr, n_nodes, cap);

  // layer 2 (+ folded final linear): fs2 = (h1r@Wc)*dinv, gather -> out (fp32)
  k_mfma<64, true><<<mblocks, 1024, 0, stream>>>(h1r, Wct, dinv, fs2, n_nodes);
  k_gather<<<gg, 1024, 0, stream>>>(fs2, srcs, gcur, qbeg, dinv,
                                    bias_out, nullptr, out, n_nodes, cap);
}

// Round 4
// 561.559 us; speedup vs baseline: 5.5980x; 5.5980x over previous
//
#include <hip/hip_runtime.h>

#define DIN 512
#define DH  64
#define BKT_SHIFT 10                // 1024 nodes per bucket
#define BKT_NODES 1024
#define MAXBKT 128                  // supports up to 131072 nodes
#define TILE 8192                   // edges per binning workgroup
#define SRC_BITS 17                 // n_nodes < 131072
#define SRC_MASK ((1u << SRC_BITS) - 1)

typedef __attribute__((ext_vector_type(8))) _Float16 half8_t;
typedef __attribute__((ext_vector_type(4))) float float4_t;

// ---- fused prep + bin (grid-partitioned):
//  block 0:    Wc=W2@Wlin -> Wct fp16, bias_out=b2@Wlin+blin
//  blocks 1-4: Wt fp16 [n][k] = W1^T slice via LDS transpose
//  blocks 5+:  bin tile (blockIdx.x-5) of edges into fixed-cap bucket regions
__global__ __launch_bounds__(256) void k_prepbin(const float* __restrict__ W1,
                                                 const float* __restrict__ W2,
                                                 const float* __restrict__ b2,
                                                 const float* __restrict__ Wlin,
                                                 const float* __restrict__ blin,
                                                 _Float16* __restrict__ Wt,
                                                 _Float16* __restrict__ Wct,
                                                 float* __restrict__ bias_out,
                                                 const int* __restrict__ src,
                                                 const int* __restrict__ dst,
                                                 int n_edges,
                                                 int* __restrict__ gcur,
                                                 unsigned int* __restrict__ tmp,
                                                 int nbkt, int cap) {
  const int tid = threadIdx.x;
  if (blockIdx.x == 0) {
    __shared__ float WcS[64 * 64];
    for (int idx = tid; idx < 64 * 64; idx += 256) {
      int i = idx >> 6, j = idx & 63;
      float s = 0.f;
      #pragma unroll 8
      for (int k = 0; k < 64; ++k) s = fmaf(W2[i * 64 + k], Wlin[k * 64 + j], s);
      WcS[idx] = s;
    }
    if (tid < 64) {
      float s = blin[tid];
      #pragma unroll 8
      for (int k = 0; k < 64; ++k) s = fmaf(b2[k], Wlin[k * 64 + tid], s);
      bias_out[tid] = s;
    }
    __syncthreads();
    for (int G = tid; G < 64 * 64 / 8; G += 256) {
      int n = G >> 3, k = (G & 7) * 8;
      half8_t h;
      #pragma unroll
      for (int j = 0; j < 8; ++j) h[j] = (_Float16)WcS[(k + j) * 64 + n];
      *(half8_t*)&Wct[(size_t)n * 64 + k] = h;
    }
  } else if (blockIdx.x <= 4) {
    __shared__ _Float16 T[64][136];
    const int k0 = (blockIdx.x - 1) * 128;
    for (int idx = tid; idx < 128 * 64; idx += 256) {
      int kk = idx >> 6, n = idx & 63;
      T[n][kk] = (_Float16)W1[(size_t)(k0 + kk) * 64 + n];
    }
    __syncthreads();
    for (int G = tid; G < 64 * 16; G += 256) {
      int n = G >> 4, g = (G & 15) * 8;
      half8_t h = *(const half8_t*)&T[n][g];
      *(half8_t*)&Wt[(size_t)n * 512 + k0 + g] = h;
    }
  } else {
    __shared__ int cnt[MAXBKT];
    __shared__ int base[MAXBKT];
    for (int b = tid; b < nbkt; b += 256) cnt[b] = 0;
    __syncthreads();
    int e0 = (blockIdx.x - 5) * TILE;
    int e1 = min(e0 + TILE, n_edges);
    for (int e = e0 + tid; e < e1; e += 256)
      atomicAdd(&cnt[dst[e] >> BKT_SHIFT], 1);
    __syncthreads();
    for (int b = tid; b < nbkt; b += 256) {
      int c = cnt[b];
      base[b] = c ? (b * cap + atomicAdd(&gcur[b], c)) : 0;
      cnt[b] = 0;
    }
    __syncthreads();
    for (int e = e0 + tid; e < e1; e += 256) {
      int d = dst[e];
      int bkt = d >> BKT_SHIFT;
      int off = atomicAdd(&cnt[bkt], 1);
      int pos = base[bkt] + off;
      if (pos < (bkt + 1) * cap)  // overflow guard (never hit for random dst)
        tmp[pos] = (unsigned int)src[e] |
                   ((unsigned int)(d & (BKT_NODES - 1)) << SRC_BITS);
    }
  }
}

// ------- per-bucket: degrees -> rowbeg/rowcnt/dinv, then place srcs (4B) ------
__global__ __launch_bounds__(256) void k_place(const unsigned int* __restrict__ tmp,
                                               const int* __restrict__ gcur,
                                               int* __restrict__ rowbeg,
                                               int* __restrict__ rowcnt,
                                               float* __restrict__ dinv,
                                               int* __restrict__ srcs,
                                               int n_nodes, int cap) {
  __shared__ int cnt[BKT_NODES];
  __shared__ int sh[256];
  const int t = threadIdx.x;
  const int bkt = blockIdx.x;
  #pragma unroll
  for (int k = 0; k < BKT_NODES / 256; ++k) cnt[t + 256 * k] = 0;
  __syncthreads();
  const int beg = bkt * cap;
  const int end = beg + min(gcur[bkt], cap);
  for (int j = beg + t; j < end; j += 256)
    atomicAdd(&cnt[tmp[j] >> SRC_BITS], 1);
  __syncthreads();
  int v[4];
  int s = 0;
  const int base = t * 4;
  #pragma unroll
  for (int k = 0; k < 4; ++k) {
    v[k] = cnt[base + k];
    s += v[k];
  }
  sh[t] = s;
  __syncthreads();
  for (int off = 1; off < 256; off <<= 1) {
    int x = sh[t];
    int y = (t >= off) ? sh[t - off] : 0;
    __syncthreads();
    sh[t] = x + y;
    __syncthreads();
  }
  int excl = sh[t] - s;
  #pragma unroll
  for (int k = 0; k < 4; ++k) {
    int idx = base + k;
    int node = (bkt << BKT_SHIFT) + idx;
    if (node < n_nodes) {
      rowbeg[node] = beg + excl;
      rowcnt[node] = v[k];
      dinv[node] = rsqrtf((float)(v[k] + 1));   // +1 self loop
    }
    cnt[idx] = excl;
    excl += v[k];
  }
  __syncthreads();
  for (int j = beg + t; j < end; j += 256) {
    unsigned int e = tmp[j];
    int r = e >> SRC_BITS;
    int pos = atomicAdd(&cnt[r], 1);
    srcs[beg + pos] = (int)(e & SRC_MASK);
  }
}

// ---- MFMA fp16 GEMM + row scaling: Ch[r,:] = (fp16)( (A[r,:] @ Bt^T) * dinv[r] )
// 1024 threads = 16 waves, 256 rows/block. Bt [64][KDIM] fp16, LDS-swizzled.
// NOTE: A-operand row index = lane&15, but C/D output row = (lane>>4)*4 + reg.
// dinv must be indexed by the OUTPUT row (bug fixed in R11).
template <int KDIM, bool A_HALF>
__global__ __launch_bounds__(1024) void k_mfma(const void* __restrict__ Ain,
                                               const _Float16* __restrict__ Bt,
                                               const float* __restrict__ dinv,
                                               _Float16* __restrict__ Ch, int M) {
  constexpr int BS_HALVES = (64 * KDIM > 16384) ? 64 * KDIM : 16384;
  __shared__ _Float16 Bs[BS_HALVES];  // 64KB (K=512) / 32KB (K=64)
  const int tid = threadIdx.x;
  for (int G = tid; G < 8 * KDIM; G += 1024) {
    int n = G / (KDIM / 8);
    int g = G % (KDIM / 8);
    half8_t h = *(const half8_t*)&Bt[(size_t)G * 8];
    *(half8_t*)&Bs[n * KDIM + ((g ^ (n & 7)) * 8)] = h;
  }
  __syncthreads();

  const int wave = tid >> 6, lane = tid & 63;
  const int quad = lane >> 4, lrow = lane & 15;
  const int row = blockIdx.x * 256 + wave * 16 + lrow;
  const int rowc = min(row, M - 1);

  float4_t acc[4] = {{0.f, 0.f, 0.f, 0.f}, {0.f, 0.f, 0.f, 0.f},
                     {0.f, 0.f, 0.f, 0.f}, {0.f, 0.f, 0.f, 0.f}};

  #pragma unroll
  for (int k0 = 0; k0 < KDIM; k0 += 32) {
    half8_t a;
    if (A_HALF) {
      a = *(const half8_t*)((const _Float16*)Ain + (size_t)rowc * KDIM + k0 + quad * 8);
    } else {
      const float* Af = (const float*)Ain + (size_t)rowc * KDIM + k0 + quad * 8;
      float4 x0 = *(const float4*)Af;
      float4 x1 = *(const float4*)(Af + 4);
      a[0] = (_Float16)x0.x; a[1] = (_Float16)x0.y;
      a[2] = (_Float16)x0.z; a[3] = (_Float16)x0.w;
      a[4] = (_Float16)x1.x; a[5] = (_Float16)x1.y;
      a[6] = (_Float16)x1.z; a[7] = (_Float16)x1.w;
    }
    const int g = (k0 >> 3) + quad;
    #pragma unroll
    for (int nb = 0; nb < 4; ++nb) {
      int n = nb * 16 + lrow;
      half8_t b = *(const half8_t*)&Bs[n * KDIM + ((g ^ (n & 7)) * 8)];
      acc[nb] = __builtin_amdgcn_mfma_f32_16x16x32_f16(a, b, acc[nb], 0, 0, 0);
    }
  }

  // per-OUTPUT-row dinv (output row = wave*16 + quad*4 + r)
  const int orow_base = blockIdx.x * 256 + wave * 16 + quad * 4;
  float dnr[4];
  #pragma unroll
  for (int r = 0; r < 4; ++r) dnr[r] = dinv[min(orow_base + r, M - 1)];

  __syncthreads();
  _Float16* scratch = Bs + wave * 1024;  // 16x64 halves per wave
  #pragma unroll
  for (int nb = 0; nb < 4; ++nb)
    #pragma unroll
    for (int r = 0; r < 4; ++r)
      scratch[(quad * 4 + r) * 64 + nb * 16 + lrow] = (_Float16)(acc[nb][r] * dnr[r]);
  const int r2 = lane >> 2, c2 = (lane & 3) * 16;
  const int row_out = blockIdx.x * 256 + wave * 16 + r2;
  half8_t o0 = *(const half8_t*)&scratch[r2 * 64 + c2];
  half8_t o1 = *(const half8_t*)&scratch[r2 * 64 + c2 + 8];
  if (row_out < M) {
    *(half8_t*)&Ch[(size_t)row_out * 64 + c2] = o0;
    *(half8_t*)&Ch[(size_t)row_out * 64 + c2 + 8] = o1;
  }
}

// ---- per-node-wave CSR gather over pre-scaled rows fs = h*dinv ---------------
// lane = 8*esub + cg; out = act( dinv[n]*( sum_e fs[s_e,:] + fs[n,:] ) + bias )
// R4: 4 independent row loads in flight per iteration (32 edges) to double MLP
// (gather is latency/MLP-bound: 9% HBM, 55% VALU, 84% occ from R2 counters).
__global__ __launch_bounds__(256) void k_gather(const _Float16* __restrict__ fs,
                                                const int* __restrict__ rowbeg,
                                                const int* __restrict__ rowcnt,
                                                const int* __restrict__ srcs,
                                                const float* __restrict__ dinv,
                                                const float* __restrict__ bias,
                                                _Float16* __restrict__ outh,
                                                float* __restrict__ outf,
                                                int n_nodes) {
  int node = __builtin_amdgcn_readfirstlane(blockIdx.x * 4 + (threadIdx.x >> 6));
  int lane = threadIdx.x & 63;
  if (node >= n_nodes) return;
  const int esub = lane >> 3;       // 0..7 edge slot
  const int ch8 = (lane & 7) * 8;   // channel group base
  const int beg = rowbeg[node];
  const int end = beg + rowcnt[node];
  float acc[8] = {0.f, 0.f, 0.f, 0.f, 0.f, 0.f, 0.f, 0.f};
  int j = beg;
  for (; j + 32 <= end; j += 32) {
    int s0 = srcs[j + esub];
    int s1 = srcs[j + 8 + esub];
    int s2 = srcs[j + 16 + esub];
    int s3 = srcs[j + 24 + esub];
    half8_t f0 = *(const half8_t*)&fs[(size_t)s0 * 64 + ch8];
    half8_t f1 = *(const half8_t*)&fs[(size_t)s1 * 64 + ch8];
    half8_t f2 = *(const half8_t*)&fs[(size_t)s2 * 64 + ch8];
    half8_t f3 = *(const half8_t*)&fs[(size_t)s3 * 64 + ch8];
    #pragma unroll
    for (int k = 0; k < 8; ++k) acc[k] += (float)f0[k];
    #pragma unroll
    for (int k = 0; k < 8; ++k) acc[k] += (float)f1[k];
    #pragma unroll
    for (int k = 0; k < 8; ++k) acc[k] += (float)f2[k];
    #pragma unroll
    for (int k = 0; k < 8; ++k) acc[k] += (float)f3[k];
  }
  if (j + 16 <= end) {
    int s0 = srcs[j + esub];
    int s1 = srcs[j + 8 + esub];
    half8_t f0 = *(const half8_t*)&fs[(size_t)s0 * 64 + ch8];
    half8_t f1 = *(const half8_t*)&fs[(size_t)s1 * 64 + ch8];
    #pragma unroll
    for (int k = 0; k < 8; ++k) acc[k] += (float)f0[k];
    #pragma unroll
    for (int k = 0; k < 8; ++k) acc[k] += (float)f1[k];
    j += 16;
  }
  for (; j < end; j += 8) {
    int idx = j + esub;
    bool act = idx < end;
    int s = srcs[act ? idx : beg];
    float w = act ? 1.f : 0.f;
    half8_t f = *(const half8_t*)&fs[(size_t)s * 64 + ch8];
    #pragma unroll
    for (int k = 0; k < 8; ++k) acc[k] = fmaf((float)f[k], w, acc[k]);
  }
  // reduce across the 8 edge slots (lane bits 3,4,5)
  #pragma unroll
  for (int m = 8; m <= 32; m <<= 1)
    #pragma unroll
    for (int k = 0; k < 8; ++k) acc[k] += __shfl_xor(acc[k], m, 64);
  if (esub == 0) {
    float dn = dinv[node];
    half8_t sf = *(const half8_t*)&fs[(size_t)node * 64 + ch8];
    float v[8];
    #pragma unroll
    for (int k = 0; k < 8; ++k)
      v[k] = fmaf(acc[k] + (float)sf[k], dn, bias[ch8 + k]);
    if (outh) {
      half8_t o;
      #pragma unroll
      for (int k = 0; k < 8; ++k) o[k] = (_Float16)fmaxf(v[k], 0.f);
      *(half8_t*)&outh[(size_t)node * 64 + ch8] = o;
    } else {
      float4 o0 = make_float4(v[0], v[1], v[2], v[3]);
      float4 o1 = make_float4(v[4], v[5], v[6], v[7]);
      *(float4*)&outf[(size_t)node * 64 + ch8] = o0;
      *(float4*)&outf[(size_t)node * 64 + ch8 + 4] = o1;
    }
  }
}

extern "C" void kernel_launch(void* const* d_in, const int* in_sizes, int n_in,
                              void* d_out, int out_size, void* d_ws, size_t ws_size,
                              hipStream_t stream) {
  const float* x    = (const float*)d_in[0];
  const int*   ei   = (const int*)d_in[1];
  const float* W1   = (const float*)d_in[2];
  const float* b1   = (const float*)d_in[3];
  const float* W2   = (const float*)d_in[4];
  const float* b2   = (const float*)d_in[5];
  const float* Wlin = (const float*)d_in[6];
  const float* blin = (const float*)d_in[7];
  float* out = (float*)d_out;

  const int n_nodes = in_sizes[0] / DIN;
  const int n_edges = in_sizes[1] / 2;
  const int* src = ei;
  const int* dst = ei + n_edges;
  const int nbkt = (n_nodes + BKT_NODES - 1) >> BKT_SHIFT;
  const int ntiles = (n_edges + TILE - 1) / TILE;
  const int cap = ((n_edges / nbkt) * 5 / 4 + 1024 + 255) & ~255;  // bucket capacity

  char* ws = (char*)d_ws;
  size_t off = 0;
  auto alloc = [&](size_t bytes) {
    void* p = ws + off;
    off += (bytes + 255) & ~(size_t)255;
    return p;
  };
  const size_t featH = (size_t)n_nodes * DH * 2;
  const size_t padE = (size_t)nbkt * cap;
  _Float16*     fs1      = (_Float16*)alloc(featH);   // (x@W1)*dinv fp16
  _Float16*     h1r      = (_Float16*)alloc(featH);   // relu'd layer-1 out, fp16
  _Float16*     fs2      = (_Float16*)alloc(featH);   // (h1r@Wc)*dinv fp16
  unsigned int* tmp      = (unsigned int*)alloc(padE * 4);
  int*          srcs     = (int*)alloc(padE * 4);
  float*        dinv     = (float*)alloc((size_t)n_nodes * 4);
  int*          rowbeg   = (int*)alloc((size_t)n_nodes * 4);
  int*          rowcnt   = (int*)alloc((size_t)n_nodes * 4);
  int*          gcur     = (int*)alloc((size_t)MAXBKT * 4);
  _Float16*     Wt       = (_Float16*)alloc(64 * 512 * 2);
  _Float16*     Wct      = (_Float16*)alloc(64 * 64 * 2);
  float*        bias_out = (float*)alloc(64 * 4);

  hipMemsetAsync(gcur, 0, (size_t)nbkt * 4, stream);

  k_prepbin<<<5 + ntiles, 256, 0, stream>>>(W1, W2, b2, Wlin, blin, Wt, Wct,
                                            bias_out, src, dst, n_edges, gcur,
                                            tmp, nbkt, cap);
  k_place<<<nbkt, 256, 0, stream>>>(tmp, gcur, rowbeg, rowcnt, dinv, srcs,
                                    n_nodes, cap);

  const int mblocks = (n_nodes + 255) / 256;
  const int agblocks = (n_nodes + 3) / 4;

  // layer 1: fs1 = (x@W1)*dinv (fp16 MFMA), gather -> h1r (fp16, ReLU fused)
  k_mfma<512, false><<<mblocks, 1024, 0, stream>>>(x, Wt, dinv, fs1, n_nodes);
  k_gather<<<agblocks, 256, 0, stream>>>(fs1, rowbeg, rowcnt, srcs, dinv, b1,
                                         h1r, nullptr, n_nodes);

  // layer 2 (+ folded final linear): fs2 = (h1r@Wc)*dinv, gather -> out (fp32)
  k_mfma<64, true><<<mblocks, 1024, 0, stream>>>(h1r, Wct, dinv, fs2, n_nodes);
  k_gather<<<agblocks, 256, 0, stream>>>(fs2, rowbeg, rowcnt, srcs, dinv,
                                         bias_out, nullptr, out, n_nodes);
}

// Round 6
// 559.203 us; speedup vs baseline: 5.6216x; 1.0042x over previous
//
#include <hip/hip_runtime.h>

#define DIN 512
#define DH  64
#define BKT_SHIFT 10                // 1024 nodes per bucket
#define BKT_NODES 1024
#define MAXBKT 128                  // supports up to 131072 nodes
#define TILE 8192                   // edges per binning workgroup
#define SRC_BITS 17                 // n_nodes < 131072
#define SRC_MASK ((1u << SRC_BITS) - 1)

typedef __attribute__((ext_vector_type(8))) _Float16 half8_t;
typedef __attribute__((ext_vector_type(4))) float float4_t;

// ---- fused prep + bin (grid-partitioned):
//  block 0:    Wc=W2@Wlin -> Wct fp16, bias_out=b2@Wlin+blin
//  blocks 1-4: Wt fp16 [n][k] = W1^T slice via LDS transpose
//  blocks 5+:  bin tile (blockIdx.x-5) of edges into fixed-cap bucket regions
//              (dst tile staged in LDS: one global read of dst instead of two)
__global__ __launch_bounds__(256) void k_prepbin(const float* __restrict__ W1,
                                                 const float* __restrict__ W2,
                                                 const float* __restrict__ b2,
                                                 const float* __restrict__ Wlin,
                                                 const float* __restrict__ blin,
                                                 _Float16* __restrict__ Wt,
                                                 _Float16* __restrict__ Wct,
                                                 float* __restrict__ bias_out,
                                                 const int* __restrict__ src,
                                                 const int* __restrict__ dst,
                                                 int n_edges,
                                                 int* __restrict__ gcur,
                                                 unsigned int* __restrict__ tmp,
                                                 int nbkt, int cap) {
  const int tid = threadIdx.x;
  if (blockIdx.x == 0) {
    __shared__ float WcS[64 * 64];
    for (int idx = tid; idx < 64 * 64; idx += 256) {
      int i = idx >> 6, j = idx & 63;
      float s = 0.f;
      #pragma unroll 8
      for (int k = 0; k < 64; ++k) s = fmaf(W2[i * 64 + k], Wlin[k * 64 + j], s);
      WcS[idx] = s;
    }
    if (tid < 64) {
      float s = blin[tid];
      #pragma unroll 8
      for (int k = 0; k < 64; ++k) s = fmaf(b2[k], Wlin[k * 64 + tid], s);
      bias_out[tid] = s;
    }
    __syncthreads();
    for (int G = tid; G < 64 * 64 / 8; G += 256) {
      int n = G >> 3, k = (G & 7) * 8;
      half8_t h;
      #pragma unroll
      for (int j = 0; j < 8; ++j) h[j] = (_Float16)WcS[(k + j) * 64 + n];
      *(half8_t*)&Wct[(size_t)n * 64 + k] = h;
    }
  } else if (blockIdx.x <= 4) {
    __shared__ _Float16 T[64][136];
    const int k0 = (blockIdx.x - 1) * 128;
    for (int idx = tid; idx < 128 * 64; idx += 256) {
      int kk = idx >> 6, n = idx & 63;
      T[n][kk] = (_Float16)W1[(size_t)(k0 + kk) * 64 + n];
    }
    __syncthreads();
    for (int G = tid; G < 64 * 16; G += 256) {
      int n = G >> 4, g = (G & 15) * 8;
      half8_t h = *(const half8_t*)&T[n][g];
      *(half8_t*)&Wt[(size_t)n * 512 + k0 + g] = h;
    }
  } else {
    __shared__ int dstS[TILE];      // 32 KB dst stage
    __shared__ int cnt[MAXBKT];
    __shared__ int base[MAXBKT];
    for (int b = tid; b < nbkt; b += 256) cnt[b] = 0;
    __syncthreads();
    int e0 = (blockIdx.x - 5) * TILE;
    int e1 = min(e0 + TILE, n_edges);
    for (int e = e0 + tid; e < e1; e += 256) {
      int d = __builtin_nontemporal_load(&dst[e]);
      dstS[e - e0] = d;
      atomicAdd(&cnt[d >> BKT_SHIFT], 1);
    }
    __syncthreads();
    for (int b = tid; b < nbkt; b += 256) {
      int c = cnt[b];
      base[b] = c ? (b * cap + atomicAdd(&gcur[b], c)) : 0;
      cnt[b] = 0;
    }
    __syncthreads();
    for (int e = e0 + tid; e < e1; e += 256) {
      int d = dstS[e - e0];
      int bkt = d >> BKT_SHIFT;
      int off = atomicAdd(&cnt[bkt], 1);
      int pos = base[bkt] + off;
      if (pos < (bkt + 1) * cap)  // overflow guard (never hit for random dst)
        tmp[pos] = (unsigned int)__builtin_nontemporal_load(&src[e]) |
                   ((unsigned int)(d & (BKT_NODES - 1)) << SRC_BITS);
    }
  }
}

// ------- per-bucket: degrees -> rowmeta{beg,cnt}/dinv, then place srcs (4B) ---
__global__ __launch_bounds__(256) void k_place(const unsigned int* __restrict__ tmp,
                                               const int* __restrict__ gcur,
                                               int2* __restrict__ rowmeta,
                                               float* __restrict__ dinv,
                                               int* __restrict__ srcs,
                                               int n_nodes, int cap) {
  __shared__ int cnt[BKT_NODES];
  __shared__ int sh[256];
  const int t = threadIdx.x;
  const int bkt = blockIdx.x;
  #pragma unroll
  for (int k = 0; k < BKT_NODES / 256; ++k) cnt[t + 256 * k] = 0;
  __syncthreads();
  const int beg = bkt * cap;
  const int end = beg + min(gcur[bkt], cap);
  for (int j = beg + t; j < end; j += 256)
    atomicAdd(&cnt[tmp[j] >> SRC_BITS], 1);
  __syncthreads();
  int v[4];
  int s = 0;
  const int base = t * 4;
  #pragma unroll
  for (int k = 0; k < 4; ++k) {
    v[k] = cnt[base + k];
    s += v[k];
  }
  sh[t] = s;
  __syncthreads();
  for (int off = 1; off < 256; off <<= 1) {
    int x = sh[t];
    int y = (t >= off) ? sh[t - off] : 0;
    __syncthreads();
    sh[t] = x + y;
    __syncthreads();
  }
  int excl = sh[t] - s;
  #pragma unroll
  for (int k = 0; k < 4; ++k) {
    int idx = base + k;
    int node = (bkt << BKT_SHIFT) + idx;
    if (node < n_nodes) {
      rowmeta[node] = make_int2(beg + excl, v[k]);
      dinv[node] = rsqrtf((float)(v[k] + 1));   // +1 self loop
    }
    cnt[idx] = excl;
    excl += v[k];
  }
  __syncthreads();
  for (int j = beg + t; j < end; j += 256) {
    unsigned int e = tmp[j];
    int r = e >> SRC_BITS;
    int pos = atomicAdd(&cnt[r], 1);
    srcs[beg + pos] = (int)(e & SRC_MASK);
  }
}

// ---- MFMA fp16 GEMM + row scaling: Ch[r,:] = (fp16)( (A[r,:] @ Bt^T) * dinv[r] )
// 1024 threads = 16 waves, 256 rows/block. Bt [64][KDIM] fp16, LDS-swizzled.
// NOTE: A-operand row index = lane&15, but C/D output row = (lane>>4)*4 + reg.
// dinv must be indexed by the OUTPUT row (bug fixed in R11).
template <int KDIM, bool A_HALF>
__global__ __launch_bounds__(1024) void k_mfma(const void* __restrict__ Ain,
                                               const _Float16* __restrict__ Bt,
                                               const float* __restrict__ dinv,
                                               _Float16* __restrict__ Ch, int M) {
  constexpr int BS_HALVES = (64 * KDIM > 16384) ? 64 * KDIM : 16384;
  __shared__ _Float16 Bs[BS_HALVES];  // 64KB (K=512) / 32KB (K=64)
  const int tid = threadIdx.x;
  for (int G = tid; G < 8 * KDIM; G += 1024) {
    int n = G / (KDIM / 8);
    int g = G % (KDIM / 8);
    half8_t h = *(const half8_t*)&Bt[(size_t)G * 8];
    *(half8_t*)&Bs[n * KDIM + ((g ^ (n & 7)) * 8)] = h;
  }
  __syncthreads();

  const int wave = tid >> 6, lane = tid & 63;
  const int quad = lane >> 4, lrow = lane & 15;
  const int row = blockIdx.x * 256 + wave * 16 + lrow;
  const int rowc = min(row, M - 1);

  float4_t acc[4] = {{0.f, 0.f, 0.f, 0.f}, {0.f, 0.f, 0.f, 0.f},
                     {0.f, 0.f, 0.f, 0.f}, {0.f, 0.f, 0.f, 0.f}};

  #pragma unroll
  for (int k0 = 0; k0 < KDIM; k0 += 32) {
    half8_t a;
    if (A_HALF) {
      a = *(const half8_t*)((const _Float16*)Ain + (size_t)rowc * KDIM + k0 + quad * 8);
    } else {
      const float* Af = (const float*)Ain + (size_t)rowc * KDIM + k0 + quad * 8;
      float4 x0 = *(const float4*)Af;
      float4 x1 = *(const float4*)(Af + 4);
      a[0] = (_Float16)x0.x; a[1] = (_Float16)x0.y;
      a[2] = (_Float16)x0.z; a[3] = (_Float16)x0.w;
      a[4] = (_Float16)x1.x; a[5] = (_Float16)x1.y;
      a[6] = (_Float16)x1.z; a[7] = (_Float16)x1.w;
    }
    const int g = (k0 >> 3) + quad;
    #pragma unroll
    for (int nb = 0; nb < 4; ++nb) {
      int n = nb * 16 + lrow;
      half8_t b = *(const half8_t*)&Bs[n * KDIM + ((g ^ (n & 7)) * 8)];
      acc[nb] = __builtin_amdgcn_mfma_f32_16x16x32_f16(a, b, acc[nb], 0, 0, 0);
    }
  }

  // per-OUTPUT-row dinv (output row = wave*16 + quad*4 + r)
  const int orow_base = blockIdx.x * 256 + wave * 16 + quad * 4;
  float dnr[4];
  #pragma unroll
  for (int r = 0; r < 4; ++r) dnr[r] = dinv[min(orow_base + r, M - 1)];

  __syncthreads();
  _Float16* scratch = Bs + wave * 1024;  // 16x64 halves per wave
  #pragma unroll
  for (int nb = 0; nb < 4; ++nb)
    #pragma unroll
    for (int r = 0; r < 4; ++r)
      scratch[(quad * 4 + r) * 64 + nb * 16 + lrow] = (_Float16)(acc[nb][r] * dnr[r]);
  const int r2 = lane >> 2, c2 = (lane & 3) * 16;
  const int row_out = blockIdx.x * 256 + wave * 16 + r2;
  half8_t o0 = *(const half8_t*)&scratch[r2 * 64 + c2];
  half8_t o1 = *(const half8_t*)&scratch[r2 * 64 + c2 + 8];
  if (row_out < M) {
    *(half8_t*)&Ch[(size_t)row_out * 64 + c2] = o0;
    *(half8_t*)&Ch[(size_t)row_out * 64 + c2 + 8] = o1;
  }
}

// ---- per-node-wave CSR gather over pre-scaled rows fs = h*dinv ---------------
// lane = 8*esub + cg; out = act( dinv[n]*( sum_e fs[s_e,:] + fs[n,:] ) + bias )
// R5: shorten the per-node serial chain (avg degree 32 -> chain-bound):
//  - rowmeta int2 (one scalar load instead of rowbeg+rowcnt)
//  - dinv/self-row/bias hoisted before the edge loop (off the critical path)
//  - non-temporal srcs loads (streamed once; don't evict fs lines)
__global__ __launch_bounds__(256) void k_gather(const _Float16* __restrict__ fs,
                                                const int2* __restrict__ rowmeta,
                                                const int* __restrict__ srcs,
                                                const float* __restrict__ dinv,
                                                const float* __restrict__ bias,
                                                _Float16* __restrict__ outh,
                                                float* __restrict__ outf,
                                                int n_nodes) {
  int node = __builtin_amdgcn_readfirstlane(blockIdx.x * 4 + (threadIdx.x >> 6));
  int lane = threadIdx.x & 63;
  if (node >= n_nodes) return;
  const int esub = lane >> 3;       // 0..7 edge slot
  const int ch8 = (lane & 7) * 8;   // channel group base
  const int2 meta = rowmeta[node];  // scalar (wave-uniform) load
  const int beg = meta.x;
  const int end = beg + meta.y;
  // independent tail operands: issue now, consume after the reduce
  const float dn = dinv[node];
  const half8_t sf = *(const half8_t*)&fs[(size_t)node * 64 + ch8];
  const float4 bs0 = *(const float4*)&bias[ch8];
  const float4 bs1 = *(const float4*)&bias[ch8 + 4];
  float acc[8] = {0.f, 0.f, 0.f, 0.f, 0.f, 0.f, 0.f, 0.f};
  int j = beg;
  for (; j + 32 <= end; j += 32) {
    int s0 = __builtin_nontemporal_load(&srcs[j + esub]);
    int s1 = __builtin_nontemporal_load(&srcs[j + 8 + esub]);
    int s2 = __builtin_nontemporal_load(&srcs[j + 16 + esub]);
    int s3 = __builtin_nontemporal_load(&srcs[j + 24 + esub]);
    half8_t f0 = *(const half8_t*)&fs[(size_t)s0 * 64 + ch8];
    half8_t f1 = *(const half8_t*)&fs[(size_t)s1 * 64 + ch8];
    half8_t f2 = *(const half8_t*)&fs[(size_t)s2 * 64 + ch8];
    half8_t f3 = *(const half8_t*)&fs[(size_t)s3 * 64 + ch8];
    #pragma unroll
    for (int k = 0; k < 8; ++k) acc[k] += (float)f0[k];
    #pragma unroll
    for (int k = 0; k < 8; ++k) acc[k] += (float)f1[k];
    #pragma unroll
    for (int k = 0; k < 8; ++k) acc[k] += (float)f2[k];
    #pragma unroll
    for (int k = 0; k < 8; ++k) acc[k] += (float)f3[k];
  }
  if (j + 16 <= end) {
    int s0 = __builtin_nontemporal_load(&srcs[j + esub]);
    int s1 = __builtin_nontemporal_load(&srcs[j + 8 + esub]);
    half8_t f0 = *(const half8_t*)&fs[(size_t)s0 * 64 + ch8];
    half8_t f1 = *(const half8_t*)&fs[(size_t)s1 * 64 + ch8];
    #pragma unroll
    for (int k = 0; k < 8; ++k) acc[k] += (float)f0[k];
    #pragma unroll
    for (int k = 0; k < 8; ++k) acc[k] += (float)f1[k];
    j += 16;
  }
  for (; j < end; j += 8) {
    int idx = j + esub;
    bool act = idx < end;
    int s = srcs[act ? idx : beg];
    float w = act ? 1.f : 0.f;
    half8_t f = *(const half8_t*)&fs[(size_t)s * 64 + ch8];
    #pragma unroll
    for (int k = 0; k < 8; ++k) acc[k] = fmaf((float)f[k], w, acc[k]);
  }
  // reduce across the 8 edge slots (lane bits 3,4,5)
  #pragma unroll
  for (int m = 8; m <= 32; m <<= 1)
    #pragma unroll
    for (int k = 0; k < 8; ++k) acc[k] += __shfl_xor(acc[k], m, 64);
  if (esub == 0) {
    float bsv[8] = {bs0.x, bs0.y, bs0.z, bs0.w, bs1.x, bs1.y, bs1.z, bs1.w};
    float v[8];
    #pragma unroll
    for (int k = 0; k < 8; ++k)
      v[k] = fmaf(acc[k] + (float)sf[k], dn, bsv[k]);
    if (outh) {
      half8_t o;
      #pragma unroll
      for (int k = 0; k < 8; ++k) o[k] = (_Float16)fmaxf(v[k], 0.f);
      *(half8_t*)&outh[(size_t)node * 64 + ch8] = o;
    } else {
      float4 o0 = make_float4(v[0], v[1], v[2], v[3]);
      float4 o1 = make_float4(v[4], v[5], v[6], v[7]);
      *(float4*)&outf[(size_t)node * 64 + ch8] = o0;
      *(float4*)&outf[(size_t)node * 64 + ch8 + 4] = o1;
    }
  }
}

extern "C" void kernel_launch(void* const* d_in, const int* in_sizes, int n_in,
                              void* d_out, int out_size, void* d_ws, size_t ws_size,
                              hipStream_t stream) {
  const float* x    = (const float*)d_in[0];
  const int*   ei   = (const int*)d_in[1];
  const float* W1   = (const float*)d_in[2];
  const float* b1   = (const float*)d_in[3];
  const float* W2   = (const float*)d_in[4];
  const float* b2   = (const float*)d_in[5];
  const float* Wlin = (const float*)d_in[6];
  const float* blin = (const float*)d_in[7];
  float* out = (float*)d_out;

  const int n_nodes = in_sizes[0] / DIN;
  const int n_edges = in_sizes[1] / 2;
  const int* src = ei;
  const int* dst = ei + n_edges;
  const int nbkt = (n_nodes + BKT_NODES - 1) >> BKT_SHIFT;
  const int ntiles = (n_edges + TILE - 1) / TILE;
  const int cap = ((n_edges / nbkt) * 5 / 4 + 1024 + 255) & ~255;  // bucket capacity

  char* ws = (char*)d_ws;
  size_t off = 0;
  auto alloc = [&](size_t bytes) {
    void* p = ws + off;
    off += (bytes + 255) & ~(size_t)255;
    return p;
  };
  const size_t featH = (size_t)n_nodes * DH * 2;
  const size_t padE = (size_t)nbkt * cap;
  _Float16*     fs1      = (_Float16*)alloc(featH);   // (x@W1)*dinv fp16
  _Float16*     h1r      = (_Float16*)alloc(featH);   // relu'd layer-1 out, fp16
  _Float16*     fs2      = (_Float16*)alloc(featH);   // (h1r@Wc)*dinv fp16
  unsigned int* tmp      = (unsigned int*)alloc(padE * 4);
  int*          srcs     = (int*)alloc(padE * 4);
  float*        dinv     = (float*)alloc((size_t)n_nodes * 4);
  int2*         rowmeta  = (int2*)alloc((size_t)n_nodes * 8);
  int*          gcur     = (int*)alloc((size_t)MAXBKT * 4);
  _Float16*     Wt       = (_Float16*)alloc(64 * 512 * 2);
  _Float16*     Wct      = (_Float16*)alloc(64 * 64 * 2);
  float*        bias_out = (float*)alloc(64 * 4);

  hipMemsetAsync(gcur, 0, (size_t)nbkt * 4, stream);

  k_prepbin<<<5 + ntiles, 256, 0, stream>>>(W1, W2, b2, Wlin, blin, Wt, Wct,
                                            bias_out, src, dst, n_edges, gcur,
                                            tmp, nbkt, cap);
  k_place<<<nbkt, 256, 0, stream>>>(tmp, gcur, rowmeta, dinv, srcs,
                                    n_nodes, cap);

  const int mblocks = (n_nodes + 255) / 256;
  const int agblocks = (n_nodes + 3) / 4;

  // layer 1: fs1 = (x@W1)*dinv (fp16 MFMA), gather -> h1r (fp16, ReLU fused)
  k_mfma<512, false><<<mblocks, 1024, 0, stream>>>(x, Wt, dinv, fs1, n_nodes);
  k_gather<<<agblocks, 256, 0, stream>>>(fs1, rowmeta, srcs, dinv, b1,
                                         h1r, nullptr, n_nodes);

  // layer 2 (+ folded final linear): fs2 = (h1r@Wc)*dinv, gather -> out (fp32)
  k_mfma<64, true><<<mblocks, 1024, 0, stream>>>(h1r, Wct, dinv, fs2, n_nodes);
  k_gather<<<agblocks, 256, 0, stream>>>(fs2, rowmeta, srcs, dinv,
                                         bias_out, nullptr, out, n_nodes);
}